// Round 2
// baseline (120.313 us; speedup 1.0000x reference)
//
#include <hip/hip_runtime.h>

// IF (integrate-and-fire) spiking layer, step == T:
//   m0 = 0.5*thr + sum_t x[t]   (per element)
//   for t in 0..T-1: spike = m > thr; out[t] = thr*spike; m -= thr*spike
//
// The validation reference recomputes the sum at high precision (fp64 numpy);
// fp32 accumulation flips the spike count for the ~10 elements whose membrane
// lands within a few fp32 ULP of a multiple of thr. So we accumulate the
// T-axis sum and run the membrane loop in double; the threshold/subtract
// steps are exact in either precision, so only the sum's rounding matters.

static constexpr int T_STEPS = 63;

__global__ __launch_bounds__(256) void IF_kernel(const float4* __restrict__ x,
                                                 const float* __restrict__ alphap,
                                                 float4* __restrict__ out,
                                                 int nvec) {
    int i = blockIdx.x * blockDim.x + threadIdx.x;
    if (i >= nvec) return;

    const float  thr_f = alphap[0];
    const double thr   = (double)thr_f;

    // Sum over the T axis in double (order-insensitive at fp32 boundary scale).
    double sx = 0.0, sy = 0.0, sz = 0.0, sw = 0.0;
    const float4* xp = x + i;
    #pragma unroll 9
    for (int t = 0; t < T_STEPS; ++t) {
        float4 v = xp[(size_t)t * nvec];
        sx += (double)v.x; sy += (double)v.y; sz += (double)v.z; sw += (double)v.w;
    }

    double mx = 0.5 * thr + sx;
    double my = 0.5 * thr + sy;
    double mz = 0.5 * thr + sz;
    double mw = 0.5 * thr + sw;

    float4* op = out + i;
    #pragma unroll
    for (int t = 0; t < T_STEPS; ++t) {
        float4 o;
        bool bx = mx > thr, by = my > thr, bz = mz > thr, bw = mw > thr;
        o.x = bx ? thr_f : 0.f;
        o.y = by ? thr_f : 0.f;
        o.z = bz ? thr_f : 0.f;
        o.w = bw ? thr_f : 0.f;
        mx -= bx ? thr : 0.0;
        my -= by ? thr : 0.0;
        mz -= bz ? thr : 0.0;
        mw -= bw ? thr : 0.0;
        op[(size_t)t * nvec] = o;
    }
}

extern "C" void kernel_launch(void* const* d_in, const int* in_sizes, int n_in,
                              void* d_out, int out_size, void* d_ws, size_t ws_size,
                              hipStream_t stream) {
    const float* x = (const float*)d_in[0];
    const float* alpha = (const float*)d_in[1];
    float* out = (float*)d_out;

    const int per_slice = in_sizes[0] / T_STEPS;   // B*S*D = 2*512*1024 = 1048576
    const int nvec = per_slice / 4;                // float4 elements per t-slice

    const int block = 256;
    const int grid = (nvec + block - 1) / block;

    IF_kernel<<<grid, block, 0, stream>>>((const float4*)x, alpha,
                                          (float4*)out, nvec);
}

// Round 3
// 117.750 us; speedup vs baseline: 1.0218x; 1.0218x over previous
//
#include <hip/hip_runtime.h>
#include <math.h>

// IF (integrate-and-fire) spiking layer, step == T:
//   m0 = 0.5*thr + sum_t x[t];  for t: spike = m > thr; out[t] = thr*spike; m -= thr*spike
//
// Closed form: since thr = 8 (power of 2) and m0 <= 67.5, every subtract
// m0 - k*thr is EXACT in f64, so the recurrence's spike pattern is
//   out[t] = thr  for t < n,  0 otherwise,   n = clamp(ceil(m0/thr - 1), 0, T)
// m0/thr (div by 2^3) and the -1.0 are exact over the value range, so this is
// bit-identical to the sequential loop that passed in R2. The T-sum is kept
// as a sequential f64 accumulation (matches the validated reference order).

static constexpr int T_STEPS = 63;

__global__ __launch_bounds__(256) void IF_kernel(const float4* __restrict__ x,
                                                 const float* __restrict__ alphap,
                                                 float4* __restrict__ out,
                                                 int nvec) {
    int i = blockIdx.x * blockDim.x + threadIdx.x;
    if (i >= nvec) return;

    const float  thr_f   = alphap[0];
    const double thr     = (double)thr_f;
    const double inv_thr = 1.0 / thr;      // 0.125, exact

    // Sequential f64 sum over the T axis (validated order, R2 absmax = 0).
    double sx = 0.0, sy = 0.0, sz = 0.0, sw = 0.0;
    const float4* xp = x + i;
    #pragma unroll 9
    for (int t = 0; t < T_STEPS; ++t) {
        float4 v = xp[(size_t)t * nvec];
        sx += (double)v.x; sy += (double)v.y; sz += (double)v.z; sw += (double)v.w;
    }

    // Spike count per component: n = clamp(ceil(m0/thr - 1), 0, T).
    auto count = [&](double s) -> int {
        double r = (0.5 * thr + s) * inv_thr - 1.0;  // exact except the m0 add (same as ref)
        int n = (int)ceil(r);
        n = n < 0 ? 0 : (n > T_STEPS ? T_STEPS : n);
        return n;
    };
    const int nx = count(sx), ny = count(sy), nz = count(sz), nw = count(sw);

    // Emit: 8.0 for the first n steps, 0 after. Pure int compare + select.
    float4* op = out + i;
    #pragma unroll 9
    for (int t = 0; t < T_STEPS; ++t) {
        float4 o;
        o.x = (t < nx) ? thr_f : 0.f;
        o.y = (t < ny) ? thr_f : 0.f;
        o.z = (t < nz) ? thr_f : 0.f;
        o.w = (t < nw) ? thr_f : 0.f;
        op[(size_t)t * nvec] = o;
    }
}

extern "C" void kernel_launch(void* const* d_in, const int* in_sizes, int n_in,
                              void* d_out, int out_size, void* d_ws, size_t ws_size,
                              hipStream_t stream) {
    const float* x = (const float*)d_in[0];
    const float* alpha = (const float*)d_in[1];
    float* out = (float*)d_out;

    const int per_slice = in_sizes[0] / T_STEPS;   // B*S*D = 1048576
    const int nvec = per_slice / 4;                // float4 elements per t-slice

    const int block = 256;
    const int grid = (nvec + block - 1) / block;

    IF_kernel<<<grid, block, 0, stream>>>((const float4*)x, alpha,
                                          (float4*)out, nvec);
}